// Round 9
// baseline (4445.954 us; speedup 1.0000x reference)
//
#include <hip/hip_runtime.h>
#include <hip/hip_cooperative_groups.h>
#include <hip/hip_bf16.h>
#include <math.h>

namespace cg = cooperative_groups;

// Problem constants
#define B 8
#define L 128
#define D 200
#define NROWS 2048          // 2 sequences * B * L
#define PAD_ID 1
#define LOG2E 1.4426950408889634f

// ==================== device GEMM tile (32x64, 2x4 micro, reg-prefetch) =============
// Computes C[row0..row0+32, col0..col0+64) += A(32xK) * W(KxN slice), raw write.
// WMODE 0: W0[k*ldw+col]; WMODE 1: proj3 W0|W1p|W2p each stride 200 (pre-offset by koff).
// GATHER: A row r = emb[ids(r)*lda + koff + k].
template<int WMODE, int GATHER>
__device__ __forceinline__ void gemm_tile(
    const float* __restrict__ A,
    const int* __restrict__ x1, const int* __restrict__ x2,
    const float* __restrict__ emb, int koff,
    const float* __restrict__ W0, const float* __restrict__ W1p,
    const float* __restrict__ W2p,
    float* __restrict__ C, int N, int K, int lda, int ldw, int ldc,
    int row0, int col0,
    float (&As)[16][34], float (&Bs)[16][68])
{
    const int tid = threadIdx.x;
    const int tx = tid & 15, ty = tid >> 4;
    float ra[2], rb[4];
    const int nK = (K + 15) >> 4;

    {
        const int kk = tid & 15;
        #pragma unroll
        for (int p = 0; p < 2; ++p) {
            int row = row0 + (tid >> 4) + p * 16;
            float v = 0.f;
            if (kk < K) {
                if (GATHER) { int id = (row < 1024) ? x1[row] : x2[row - 1024];
                              v = emb[id * lda + koff + kk]; }
                else v = A[row * lda + kk];
            }
            ra[p] = v;
        }
        const int nn = col0 + (tid & 63);
        #pragma unroll
        for (int p = 0; p < 4; ++p) {
            int kk2 = (tid >> 6) + p * 4;
            float v = 0.f;
            if (kk2 < K && nn < N) {
                if (WMODE == 1)
                    v = (nn < 200) ? W0[kk2 * 200 + nn]
                      : (nn < 400) ? W1p[kk2 * 200 + nn - 200]
                                   : W2p[kk2 * 200 + nn - 400];
                else v = W0[kk2 * ldw + nn];
            }
            rb[p] = v;
        }
    }

    float acc[2][4] = {};
    for (int kc = 0; kc < nK; ++kc) {
        __syncthreads();
        As[tid & 15][tid >> 4]        = ra[0];
        As[tid & 15][(tid >> 4) + 16] = ra[1];
        #pragma unroll
        for (int p = 0; p < 4; ++p) Bs[(tid >> 6) + p * 4][tid & 63] = rb[p];
        __syncthreads();

        if (kc + 1 < nK) {
            const int k0 = (kc + 1) * 16;
            const int kk = k0 + (tid & 15);
            #pragma unroll
            for (int p = 0; p < 2; ++p) {
                int row = row0 + (tid >> 4) + p * 16;
                float v = 0.f;
                if (kk < K) {
                    if (GATHER) { int id = (row < 1024) ? x1[row] : x2[row - 1024];
                                  v = emb[id * lda + koff + kk]; }
                    else v = A[row * lda + kk];
                }
                ra[p] = v;
            }
            const int nn = col0 + (tid & 63);
            #pragma unroll
            for (int p = 0; p < 4; ++p) {
                int kk2 = k0 + (tid >> 6) + p * 4;
                float v = 0.f;
                if (kk2 < K && nn < N) {
                    if (WMODE == 1)
                        v = (nn < 200) ? W0[kk2 * 200 + nn]
                          : (nn < 400) ? W1p[kk2 * 200 + nn - 200]
                                       : W2p[kk2 * 200 + nn - 400];
                    else v = W0[kk2 * ldw + nn];
                }
                rb[p] = v;
            }
        }

        #pragma unroll
        for (int k = 0; k < 16; ++k) {
            float a0 = As[k][ty * 2], a1 = As[k][ty * 2 + 1];
            float w0 = Bs[k][tx * 4], w1 = Bs[k][tx * 4 + 1];
            float w2 = Bs[k][tx * 4 + 2], w3 = Bs[k][tx * 4 + 3];
            acc[0][0] = fmaf(a0, w0, acc[0][0]); acc[0][1] = fmaf(a0, w1, acc[0][1]);
            acc[0][2] = fmaf(a0, w2, acc[0][2]); acc[0][3] = fmaf(a0, w3, acc[0][3]);
            acc[1][0] = fmaf(a1, w0, acc[1][0]); acc[1][1] = fmaf(a1, w1, acc[1][1]);
            acc[1][2] = fmaf(a1, w2, acc[1][2]); acc[1][3] = fmaf(a1, w3, acc[1][3]);
        }
    }

    #pragma unroll
    for (int i = 0; i < 2; ++i) {
        const int row = row0 + ty * 2 + i;
        #pragma unroll
        for (int j = 0; j < 4; ++j) {
            const int col = col0 + tx * 4 + j;
            if (col < N) C[row * ldc + col] = acc[i][j];
        }
    }
}

// ==================== mega-kernel args ====================
struct MArgs {
    const int *x1, *x2;
    const float *emb, *Wh_w, *Wh_b, *W1_w, *W2_w, *bvec, *cptr,
                *Wf1_w, *Wf2_w, *Wf2_b, *Ws1_w, *Ws1_b, *Ws_w, *Ws_b,
                *F1_w, *F1_b, *F2_w, *F2_b;
    float *h, *hP, *sfw, *sbw, *u, *v1, *bvP, *partM, *hsumP, *P, *y;
};

// ==================== mega1: h -> hcomb -> proj3 -> p3comb ====================
__global__ __launch_bounds__(256, 4)
void mega1_k(MArgs a)
{
    __shared__ float As[16][34];
    __shared__ float Bs[16][68];
    cg::grid_group grid = cg::this_grid();
    const int bid = blockIdx.x, tid = threadIdx.x;

    // Phase 1: h parts (k-split x4, 1024 units exactly)
    {
        const int z = bid >> 8, t = bid & 255;
        gemm_tile<0, 1>(nullptr, a.x1, a.x2, a.emb, z * 50,
                        a.Wh_w + z * 50 * 200, nullptr, nullptr,
                        a.P + (size_t)z * 409600, 200, 50, 200, 200, 200,
                        (t >> 2) * 32, (t & 3) * 64, As, Bs);
    }
    grid.sync();
    // Phase 2: h = elu(sum4 + Wh_b)
    for (int idx = bid * 256 + tid; idx < 409600; idx += 262144) {
        const int col = idx % 200;
        float s = a.P[idx] + a.P[idx + 409600] + a.P[idx + 819200]
                + a.P[idx + 1228800] + a.Wh_b[col];
        a.h[idx] = (s > 0.f) ? s : expm1f(s);
    }
    grid.sync();
    // Phase 3: proj3 parts (2560 units)
    for (int w = bid; w < 2560; w += 1024) {
        const int z = w / 640, t = w - z * 640;
        const int bn = t % 10, bm = t / 10;
        gemm_tile<1, 0>(a.h + z * 50, nullptr, nullptr, nullptr, 0,
                        a.W1_w + z * 50 * 200, a.W2_w + z * 50 * 200,
                        a.Wf2_w + z * 50 * 200,
                        a.P + (size_t)z * 1228800, 600, 50, 200, 200, 600,
                        bm * 32, bn * 64, As, Bs);
    }
    grid.sync();
    // Phase 4: hP = precompute epilogue over sum4
    const float k1 = 2.0f * LOG2E / a.cptr[0];
    for (int idx = bid * 256 + tid; idx < 1228800; idx += 262144) {
        const int col = idx % 600;
        float v = a.P[idx] + a.P[idx + 1228800] + a.P[idx + 2457600]
                + a.P[idx + 3686400];
        if (col < 200)      v = (v + a.bvec[col]) * k1;
        else if (col < 400) v = v * k1;
        else                v += a.Wf2_b[col - 400];
        a.hP[idx] = v;
    }
}

// ==================== attention partial (unchanged, separate launch) ==============
__global__ __launch_bounds__(256)
void attn_part4_k(const float* __restrict__ h, const float* __restrict__ hP,
                  const float* __restrict__ cptr,
                  const int* __restrict__ x1, const int* __restrict__ x2,
                  float* __restrict__ part, float* __restrict__ hsumP)
{
    const int blk = blockIdx.x;          // 0..2047
    const int jq  = blk & 3;
    const int qc  = (blk >> 2) & 31;
    const int sb  = blk >> 7;            // 0..15
    const int i0  = qc * 4;
    const int base = sb * 128;
    const int j0 = jq * 32, j1 = j0 + 32;
    const int d = threadIdx.x;
    const int* ids = (sb < 8) ? x1 : x2;
    const int loc0 = (sb & 7) * 128;

    const float cval = cptr[0];
    const float mcoef = -2.0f * cval * LOG2E;

    const unsigned long long km =
        __ballot(ids[loc0 + j0 + (threadIdx.x & 31)] == PAD_ID);

    float pq[4];
    #pragma unroll
    for (int q = 0; q < 4; ++q)
        pq[q] = (d < D) ? hP[(base + i0 + q) * 600 + d] : 0.f;

    float lf[4] = {}, af[4] = {}, lb[4] = {}, ab[4] = {};
    float hsum = 0.f;

    auto sc = [&](float p, float h2k) -> float {
        float e2 = __builtin_amdgcn_exp2f(p + h2k);
        return __builtin_amdgcn_exp2f(mcoef * __builtin_amdgcn_rcpf(e2 + 1.0f));
    };
    auto ldrow = [&](int j, float& h2k, float& hj) {
        h2k = 0.f; hj = 0.f;
        if (d < D) {
            h2k = hP[(base + j) * 600 + 200 + d];
            hj  = h[(base + j) * 200 + d];
        }
    };

    const int aEnd = (i0 < j1) ? i0 : j1;
    for (int j = j0; j < aEnd; j += 2) {
        float h2a, ha, h2b, hb;
        ldrow(j, h2a, ha); ldrow(j + 1, h2b, hb);
        hsum += ha + hb;
        if (!((km >> (j - j0)) & 1ull)) {
            #pragma unroll
            for (int q = 0; q < 4; ++q) {
                float w = sc(pq[q], h2a);
                lb[q] += w; ab[q] = fmaf(w, ha, ab[q]);
            }
        }
        if (!((km >> (j + 1 - j0)) & 1ull)) {
            #pragma unroll
            for (int q = 0; q < 4; ++q) {
                float w = sc(pq[q], h2b);
                lb[q] += w; ab[q] = fmaf(w, hb, ab[q]);
            }
        }
    }
    if (i0 >= j0 && i0 < j1) {
        #pragma unroll
        for (int jj = 0; jj < 4; ++jj) {
            const int j = i0 + jj;
            float h2a, ha;
            ldrow(j, h2a, ha);
            hsum += ha;
            if (!((km >> (j - j0)) & 1ull)) {
                #pragma unroll
                for (int q = 0; q < 4; ++q) {
                    if (jj == q) continue;
                    float w = sc(pq[q], h2a);
                    if (jj > q) { lf[q] += w; af[q] = fmaf(w, ha, af[q]); }
                    else        { lb[q] += w; ab[q] = fmaf(w, ha, ab[q]); }
                }
            }
        }
    }
    const int cs = (i0 + 4 > j0) ? i0 + 4 : j0;
    for (int j = cs; j < j1; j += 2) {
        float h2a, ha, h2b, hb;
        ldrow(j, h2a, ha); ldrow(j + 1, h2b, hb);
        hsum += ha + hb;
        if (!((km >> (j - j0)) & 1ull)) {
            #pragma unroll
            for (int q = 0; q < 4; ++q) {
                float w = sc(pq[q], h2a);
                lf[q] += w; af[q] = fmaf(w, ha, af[q]);
            }
        }
        if (!((km >> (j + 1 - j0)) & 1ull)) {
            #pragma unroll
            for (int q = 0; q < 4; ++q) {
                float w = sc(pq[q], h2b);
                lf[q] += w; af[q] = fmaf(w, hb, af[q]);
            }
        }
    }

    if (d < D) {
        float* pp = part + (size_t)blk * 3200;   // [blk][16][200]
        #pragma unroll
        for (int q = 0; q < 4; ++q) {
            pp[(q * 4 + 0) * 200 + d] = lf[q];
            pp[(q * 4 + 1) * 200 + d] = af[q];
            pp[(q * 4 + 2) * 200 + d] = lb[q];
            pp[(q * 4 + 3) * 200 + d] = ab[q];
        }
        hsumP[(jq * 16 + sb) * 200 + d] = hsum;
    }
}

// ==================== mega2: attn_comb ... final2 ====================
__global__ __launch_bounds__(256, 4)
void mega2_k(MArgs a)
{
    __shared__ float As[16][34];
    __shared__ float Bs[16][68];
    __shared__ float red4[4][64];
    __shared__ float feats[8][50];
    __shared__ float red256[256];
    cg::grid_group grid = cg::this_grid();
    const int bid = blockIdx.x, tid = threadIdx.x;

    // Phase A: attn combine (512 units)
    if (bid < 512 && tid < D) {
        const int sb = bid >> 5, qc = bid & 31;
        const int i0 = qc * 4, base = sb * 128;
        const int d = tid;
        const int* ids = (sb < 8) ? a.x1 : a.x2;
        const int loc0 = (sb & 7) * 128;
        float hs = 0.f;
        #pragma unroll
        for (int jq = 0; jq < 4; ++jq) hs += a.hsumP[(jq * 16 + sb) * 200 + d];
        const float fb = hs * (1.0f / 128.0f);
        #pragma unroll
        for (int q = 0; q < 4; ++q) {
            const bool mi = (ids[loc0 + i0 + q] == PAD_ID);
            float lf = 0.f, af = 0.f, lb = 0.f, ab = 0.f;
            #pragma unroll
            for (int jq = 0; jq < 4; ++jq) {
                const float* pp = a.P + ((size_t)(sb * 128 + qc * 4 + jq)) * 3200
                                       + (q * 4) * 200;
                lf += pp[d]; af += pp[200 + d]; lb += pp[400 + d]; ab += pp[600 + d];
            }
            a.sfw[(base + i0 + q) * 200 + d] = (!mi && lf > 0.f) ? af / lf : fb;
            a.sbw[(base + i0 + q) * 200 + d] = (!mi && lb > 0.f) ? ab / lb : fb;
        }
    }
    grid.sync();
    // Phase B: Wf1 parts (2048 units, M=4096 over sfw|sbw)
    for (int w = bid; w < 2048; w += 1024) {
        const int z = w >> 9, t = w & 511;
        gemm_tile<0, 0>(a.sfw + z * 50, nullptr, nullptr, nullptr, 0,
                        a.Wf1_w + z * 50 * 200, nullptr, nullptr,
                        a.P + (size_t)z * 819200, 200, 50, 200, 200, 200,
                        (t >> 2) * 32, (t & 3) * 64, As, Bs);
    }
    grid.sync();
    // Phase C: u = gate(sum4 + hf2)
    for (int idx = bid * 256 + tid; idx < 819200; idx += 262144) {
        const int row = idx / 200, col = idx - row * 200;
        const int sr = row & 2047, half = row >> 11;
        float g = a.P[idx] + a.P[idx + 819200] + a.P[idx + 1638400]
                + a.P[idx + 2457600] + a.hP[sr * 600 + 400 + col];
        float f = 1.0f / (1.0f + __expf(-g));
        float s = a.sfw[idx];
        float hv = a.h[sr * 200 + col];
        a.u[sr * 400 + half * 200 + col] = f * hv + (1.f - f) * s;
    }
    grid.sync();
    // Phase D: Ws1 parts (1792 units)
    for (int w = bid; w < 1792; w += 1024) {
        const int z = w / 448, t = w - z * 448;
        const int bn = t % 7, bm = t / 7;
        gemm_tile<0, 0>(a.u + z * 100, nullptr, nullptr, nullptr, 0,
                        a.Ws1_w + z * 100 * 400, nullptr, nullptr,
                        a.P + (size_t)z * 819200, 400, 100, 400, 400, 400,
                        bm * 32, bn * 64, As, Bs);
    }
    grid.sync();
    // Phase E: v1 = elu(sum4 + Ws1_b)
    for (int idx = bid * 256 + tid; idx < 819200; idx += 262144) {
        const int col = idx % 400;
        float s = a.P[idx] + a.P[idx + 819200] + a.P[idx + 1638400]
                + a.P[idx + 2457600] + a.Ws1_b[col];
        a.v1[idx] = (s > 0.f) ? s : expm1f(s);
    }
    grid.sync();
    // Phase F: Ws parts (1792 units)
    for (int w = bid; w < 1792; w += 1024) {
        const int z = w / 448, t = w - z * 448;
        const int bn = t % 7, bm = t / 7;
        gemm_tile<0, 0>(a.v1 + z * 100, nullptr, nullptr, nullptr, 0,
                        a.Ws_w + z * 100 * 400, nullptr, nullptr,
                        a.P + (size_t)z * 819200, 400, 100, 400, 400, 400,
                        bm * 32, bn * 64, As, Bs);
    }
    grid.sync();
    // Phase G: bvP = l-split partial of sum_l u*(sum4+Ws_b)  (448 units)
    if (bid < 448) {
        const int sb = bid & 15, nt = (bid >> 4) % 7, lz = bid / 112;
        const int nl = tid & 63, lg = tid >> 6;
        const int n = nt * 64 + nl;
        float acc = 0.f;
        if (n < 400) {
            const float bn = a.Ws_b[n];
            const int r0 = sb * 128 + lz * 32 + lg * 8;
            for (int l = 0; l < 8; ++l) {
                const int idx = (r0 + l) * 400 + n;
                float av = a.P[idx] + a.P[idx + 819200] + a.P[idx + 1638400]
                         + a.P[idx + 2457600] + bn;
                acc = fmaf(a.u[idx], av, acc);
            }
        }
        red4[lg][nl] = acc;
        __syncthreads();
        if (tid < 64 && n < 400)
            a.bvP[lz * 6400 + sb * 400 + n]
                = red4[0][nl] + red4[1][nl] + red4[2][nl] + red4[3][nl];
    }
    grid.sync();
    // Phase H: final1 partials (32 units)
    if (bid < 32) {
        const int seg = bid >> 3, kr0 = (bid & 7) * 50;
        for (int idx = tid; idx < 400; idx += 256) {
            int b = idx / 50, kk = idx - b * 50;
            float cv = 0.f, rv = 0.f;
            #pragma unroll
            for (int z = 0; z < 4; ++z) {
                cv += a.bvP[z * 6400 + b * 400 + kr0 + kk];
                rv += a.bvP[z * 6400 + (8 + b) * 400 + kr0 + kk];
            }
            feats[b][kk] = (seg == 0) ? cv : (seg == 1) ? rv
                         : (seg == 2) ? (cv - rv) : (cv * rv);
        }
        __syncthreads();
        if (tid < 200) {
            const int kbase = seg * 400 + kr0;
            float acc[8] = {};
            #pragma unroll 5
            for (int kk = 0; kk < 50; ++kk) {
                float w = a.F1_w[(kbase + kk) * 200 + tid];
                #pragma unroll
                for (int b = 0; b < 8; ++b)
                    acc[b] = fmaf(feats[b][kk], w, acc[b]);
            }
            #pragma unroll
            for (int b = 0; b < 8; ++b)
                a.partM[(bid * 8 + b) * 200 + tid] = acc[b];
        }
    }
    grid.sync();
    // Phase I: final2 (8 units)
    if (bid < 8) {
        float v = 0.f;
        if (tid < 200) {
            float s = a.F1_b[tid];
            #pragma unroll 8
            for (int t2 = 0; t2 < 32; ++t2)
                s += a.partM[(t2 * 8 + bid) * 200 + tid];
            v = fmaxf(s, 0.f) * a.F2_w[tid];
        }
        red256[tid] = v;
        __syncthreads();
        for (int off = 128; off; off >>= 1) {
            if (tid < off) red256[tid] += red256[tid + off];
            __syncthreads();
        }
        if (tid == 0) a.y[bid] = red256[0] + a.F2_b[0];
    }
}

// ==================== discrete fallback kernels (round-8) ====================
template<int WMODE, int EMODE, int GATHER>
__global__ __launch_bounds__(256)
void gemm2_k(const float* __restrict__ A,
             const int* __restrict__ x1, const int* __restrict__ x2,
             const float* __restrict__ emb,
             const float* __restrict__ W0, const float* __restrict__ W1p,
             const float* __restrict__ W2p, const float* __restrict__ bias,
             const float* __restrict__ aux1, const float* __restrict__ aux2,
             float* __restrict__ C, int M, int N, int K,
             int lda, int ldw, int ldc)
{
    __shared__ float As[16][34];
    __shared__ float Bs[16][68];
    const int koff = blockIdx.z * K;
    A += koff;
    const float* W0o = W0; const float* W1o = W1p; const float* W2o = W2p;
    if (WMODE == 0) { W0o += (size_t)koff * ldw; }
    else { W0o += koff * 200; W1o += koff * 200; W2o += koff * 200; }
    C += (size_t)blockIdx.z * M * ldc;

    const int row0 = blockIdx.y * 32, col0 = blockIdx.x * 64;
    const int tid = threadIdx.x;
    const int tx = tid & 15, ty = tid >> 4;

    gemm_tile<WMODE, GATHER>(A, x1, x2, emb, koff, W0o, W1o, W2o,
                             C, N, K, lda, ldw, ldc, row0, col0, As, Bs);
    // epilogue rewrite for EMODE != 0 (re-read raw C and transform)
    if (EMODE != 0) {
        __syncthreads();
        #pragma unroll
        for (int i = 0; i < 2; ++i) {
            const int row = row0 + ty * 2 + i;
            #pragma unroll
            for (int j = 0; j < 4; ++j) {
                const int col = col0 + tx * 4 + j;
                if (col >= N) continue;
                float v = C[row * ldc + col];
                if (EMODE == 2) {
                    const int sr = row & 2047, half = row >> 11;
                    float g = v + aux2[sr * 600 + 400 + col];
                    float f = 1.0f / (1.0f + __expf(-g));
                    float s = A[row * lda + col - koff + koff]; // A already offset; col index
                    s = A[row * lda + col];
                    float hv = aux1[sr * 200 + col];
                    C[sr * 400 + half * 200 + col] = f * hv + (1.f - f) * s;
                } else if (EMODE == 3) {
                    const float k1 = 2.0f * LOG2E / aux2[0];
                    if (col < 200)      v = (v + aux1[col]) * k1;
                    else if (col < 400) v = v * k1;
                    else                v += bias[col - 400];
                    C[row * ldc + col] = v;
                } else {
                    if (bias) v += bias[col];
                    if (EMODE == 1) v = (v > 0.f) ? v : expm1f(v);
                    C[row * ldc + col] = v;
                }
            }
        }
    } else if (bias) {
        #pragma unroll
        for (int i = 0; i < 2; ++i) {
            const int row = row0 + ty * 2 + i;
            #pragma unroll
            for (int j = 0; j < 4; ++j) {
                const int col = col0 + tx * 4 + j;
                if (col < N) C[row * ldc + col] += bias[col];
            }
        }
    }
}

__global__ __launch_bounds__(256)
void hcomb_k(const float* __restrict__ P, const float* __restrict__ bias,
             float* __restrict__ h)
{
    const int idx = blockIdx.x * 256 + threadIdx.x;
    if (idx >= NROWS * 200) return;
    const int col = idx % 200;
    float s = P[idx] + P[idx + 409600] + P[idx + 819200] + P[idx + 1228800]
            + bias[col];
    h[idx] = (s > 0.f) ? s : expm1f(s);
}

__global__ __launch_bounds__(256)
void p3comb_k(const float* __restrict__ P, const float* __restrict__ bvec,
              const float* __restrict__ Wf2_b, const float* __restrict__ cptr,
              float* __restrict__ hP)
{
    const int idx = blockIdx.x * 256 + threadIdx.x;
    if (idx >= NROWS * 600) return;
    const int col = idx % 600;
    float v = P[idx] + P[idx + 1228800] + P[idx + 2 * 1228800] + P[idx + 3 * 1228800];
    const float k1 = 2.0f * LOG2E / cptr[0];
    if (col < 200)      v = (v + bvec[col]) * k1;
    else if (col < 400) v = v * k1;
    else                v += Wf2_b[col - 400];
    hP[idx] = v;
}

__global__ __launch_bounds__(256)
void ugate_k(const float* __restrict__ P, const float* __restrict__ h,
             const float* __restrict__ hP, const float* __restrict__ sfw,
             float* __restrict__ u)
{
    const int idx = blockIdx.x * 256 + threadIdx.x;
    if (idx >= 2 * NROWS * 200) return;
    const int row = idx / 200, col = idx - row * 200;
    const int sr = row & 2047, half = row >> 11;
    float g = P[idx] + P[idx + 819200] + P[idx + 2 * 819200] + P[idx + 3 * 819200]
            + hP[sr * 600 + 400 + col];
    float f = 1.0f / (1.0f + __expf(-g));
    float s = sfw[idx];
    float hv = h[sr * 200 + col];
    u[sr * 400 + half * 200 + col] = f * hv + (1.f - f) * s;
}

__global__ __launch_bounds__(256)
void attn_comb4_k(const float* __restrict__ part, const float* __restrict__ hsumP,
                  const int* __restrict__ x1, const int* __restrict__ x2,
                  float* __restrict__ s_fw, float* __restrict__ s_bw)
{
    const int g = blockIdx.x;
    const int sb = g >> 5, qc = g & 31;
    const int i0 = qc * 4, base = sb * 128;
    const int d = threadIdx.x;
    if (d >= D) return;
    const int* ids = (sb < 8) ? x1 : x2;
    const int loc0 = (sb & 7) * 128;
    float hs = 0.f;
    #pragma unroll
    for (int jq = 0; jq < 4; ++jq) hs += hsumP[(jq * 16 + sb) * 200 + d];
    const float fb = hs * (1.0f / 128.0f);
    #pragma unroll
    for (int q = 0; q < 4; ++q) {
        const bool mi = (ids[loc0 + i0 + q] == PAD_ID);
        float lf = 0.f, af = 0.f, lb = 0.f, ab = 0.f;
        #pragma unroll
        for (int jq = 0; jq < 4; ++jq) {
            const float* pp = part + ((size_t)(sb * 128 + qc * 4 + jq)) * 3200
                                   + (q * 4) * 200;
            lf += pp[d]; af += pp[200 + d]; lb += pp[400 + d]; ab += pp[600 + d];
        }
        s_fw[(base + i0 + q) * 200 + d] = (!mi && lf > 0.f) ? af / lf : fb;
        s_bw[(base + i0 + q) * 200 + d] = (!mi && lb > 0.f) ? ab / lb : fb;
    }
}

__global__ __launch_bounds__(256)
void v1comb_k(const float* __restrict__ P, const float* __restrict__ bias,
              float* __restrict__ v1)
{
    const int idx = blockIdx.x * 256 + threadIdx.x;
    if (idx >= NROWS * 400) return;
    const int col = idx % 400;
    float s = P[idx] + P[idx + 819200] + P[idx + 2 * 819200] + P[idx + 3 * 819200]
            + bias[col];
    v1[idx] = (s > 0.f) ? s : expm1f(s);
}

__global__ __launch_bounds__(256)
void bvcomb_k(const float* __restrict__ u, const float* __restrict__ P,
              const float* __restrict__ bias, float* __restrict__ bvP)
{
    __shared__ float red[4][64];
    const int sb = blockIdx.x, nt = blockIdx.y, lz = blockIdx.z;
    const int tid = threadIdx.x;
    const int nl = tid & 63, lg = tid >> 6;
    const int n = nt * 64 + nl;
    float acc = 0.f;
    if (n < 400) {
        const float bn = bias[n];
        const int r0 = sb * 128 + lz * 32 + lg * 8;
        for (int l = 0; l < 8; ++l) {
            const int idx = (r0 + l) * 400 + n;
            float a = P[idx] + P[idx + 819200] + P[idx + 2 * 819200]
                    + P[idx + 3 * 819200] + bn;
            acc = fmaf(u[idx], a, acc);
        }
    }
    red[lg][nl] = acc;
    __syncthreads();
    if (tid < 64 && n < 400)
        bvP[lz * 6400 + sb * 400 + n] = red[0][nl] + red[1][nl] + red[2][nl] + red[3][nl];
}

template<int NS>
__global__ __launch_bounds__(256)
void final1_part_k(const float* __restrict__ bvP, const float* __restrict__ F1w,
                   float* __restrict__ part)
{
    __shared__ float feats[8][50];
    const int bid = blockIdx.x;
    const int seg = bid >> 3;
    const int kr0 = (bid & 7) * 50;
    const int tid = threadIdx.x;
    for (int idx = tid; idx < 400; idx += 256) {
        int b = idx / 50, kk = idx - b * 50;
        float cv = 0.f, rv = 0.f;
        #pragma unroll
        for (int z = 0; z < NS; ++z) {
            cv += bvP[z * 6400 + b * 400 + kr0 + kk];
            rv += bvP[z * 6400 + (8 + b) * 400 + kr0 + kk];
        }
        feats[b][kk] = (seg == 0) ? cv : (seg == 1) ? rv
                     : (seg == 2) ? (cv - rv) : (cv * rv);
    }
    __syncthreads();
    const int n = tid;
    if (n >= 200) return;
    const int kbase = seg * 400 + kr0;
    float acc[8] = {};
    #pragma unroll 5
    for (int kk = 0; kk < 50; ++kk) {
        float w = F1w[(kbase + kk) * 200 + n];
        #pragma unroll
        for (int b = 0; b < 8; ++b)
            acc[b] = fmaf(feats[b][kk], w, acc[b]);
    }
    #pragma unroll
    for (int b = 0; b < 8; ++b)
        part[(bid * 8 + b) * 200 + n] = acc[b];
}

__global__ __launch_bounds__(256)
void final2_k(const float* __restrict__ part, const float* __restrict__ F1b,
              const float* __restrict__ F2w, const float* __restrict__ F2b,
              float* __restrict__ y)
{
    __shared__ float red[256];
    const int b = blockIdx.x, tid = threadIdx.x;
    float v = 0.f;
    if (tid < 200) {
        float s = F1b[tid];
        #pragma unroll 8
        for (int t = 0; t < 32; ++t)
            s += part[(t * 8 + b) * 200 + tid];
        v = fmaxf(s, 0.f) * F2w[tid];
    }
    red[tid] = v;
    __syncthreads();
    for (int off = 128; off; off >>= 1) {
        if (tid < off) red[tid] += red[tid + off];
        __syncthreads();
    }
    if (tid == 0) y[b] = red[0] + F2b[0];
}

extern "C" void kernel_launch(void* const* d_in, const int* in_sizes, int n_in,
                              void* d_out, int out_size, void* d_ws, size_t ws_size,
                              hipStream_t stream)
{
    const int*   x1    = (const int*)d_in[0];
    const int*   x2    = (const int*)d_in[1];
    const float* emb   = (const float*)d_in[2];
    const float* Wh_w  = (const float*)d_in[3];
    const float* Wh_b  = (const float*)d_in[4];
    const float* W1_w  = (const float*)d_in[5];
    const float* W2_w  = (const float*)d_in[6];
    const float* bvec  = (const float*)d_in[7];
    const float* cptr  = (const float*)d_in[8];
    const float* Wf1_w = (const float*)d_in[9];
    const float* Wf2_w = (const float*)d_in[10];
    const float* Wf2_b = (const float*)d_in[11];
    const float* Ws1_w = (const float*)d_in[12];
    const float* Ws1_b = (const float*)d_in[13];
    const float* Ws_w  = (const float*)d_in[14];
    const float* Ws_b  = (const float*)d_in[15];
    const float* F1_w  = (const float*)d_in[16];
    const float* F1_b  = (const float*)d_in[17];
    const float* F2_w  = (const float*)d_in[18];
    const float* F2_b  = (const float*)d_in[19];
    float* y = (float*)d_out;

    float* ws = (float*)d_ws;
    float* h     = ws;                    // 409600
    float* hP    = h     + 409600;        // 1228800
    float* sfw   = hP    + 1228800;       // 409600
    float* sbw   = sfw   + 409600;        // 409600
    float* u     = sbw   + 409600;        // 819200
    float* v1    = u     + 819200;        // 819200
    float* bvP   = v1    + 819200;        // 25600
    float* partM = bvP   + 25600;         // 51200
    float* hsumP = partM + 51200;         // 12800
    float* P     = hsumP + 12800;         // 6553600
    const size_t need_bytes = (size_t)(10739200) * 4;

    dim3 blk(256);
    const bool big = (ws_size >= need_bytes);

    if (big) {
        MArgs a;
        a.x1 = x1; a.x2 = x2; a.emb = emb; a.Wh_w = Wh_w; a.Wh_b = Wh_b;
        a.W1_w = W1_w; a.W2_w = W2_w; a.bvec = bvec; a.cptr = cptr;
        a.Wf1_w = Wf1_w; a.Wf2_w = Wf2_w; a.Wf2_b = Wf2_b;
        a.Ws1_w = Ws1_w; a.Ws1_b = Ws1_b; a.Ws_w = Ws_w; a.Ws_b = Ws_b;
        a.F1_w = F1_w; a.F1_b = F1_b; a.F2_w = F2_w; a.F2_b = F2_b;
        a.h = h; a.hP = hP; a.sfw = sfw; a.sbw = sbw; a.u = u; a.v1 = v1;
        a.bvP = bvP; a.partM = partM; a.hsumP = hsumP; a.P = P; a.y = y;
        void* kp[] = { (void*)&a };

        hipError_t e1 = hipLaunchCooperativeKernel(
            (const void*)mega1_k, dim3(1024), blk, kp, 0, stream);
        if (e1 == hipSuccess) {
            attn_part4_k<<<dim3(2048), blk, 0, stream>>>(h, hP, cptr, x1, x2, P, hsumP);
            hipError_t e2 = hipLaunchCooperativeKernel(
                (const void*)mega2_k, dim3(1024), blk, kp, 0, stream);
            if (e2 == hipSuccess) return;
            // finish discretely after attn_part
            attn_comb4_k<<<dim3(512), blk, 0, stream>>>(P, hsumP, x1, x2, sfw, sbw);
            gemm2_k<0, 0, 0><<<dim3(4, 128, 4), blk, 0, stream>>>(
                sfw, nullptr, nullptr, nullptr, Wf1_w, nullptr, nullptr, nullptr,
                nullptr, nullptr, P, 2 * NROWS, 200, 50, 200, 200, 200);
            ugate_k<<<dim3(3200), blk, 0, stream>>>(P, h, hP, sfw, u);
            gemm2_k<0, 0, 0><<<dim3(7, 64, 4), blk, 0, stream>>>(
                u, nullptr, nullptr, nullptr, Ws1_w, nullptr, nullptr, nullptr,
                nullptr, nullptr, P, NROWS, 400, 100, 400, 400, 400);
            v1comb_k<<<dim3(3200), blk, 0, stream>>>(P, Ws1_b, v1);
            gemm2_k<0, 0, 0><<<dim3(7, 64, 4), blk, 0, stream>>>(
                v1, nullptr, nullptr, nullptr, Ws_w, nullptr, nullptr, nullptr,
                nullptr, nullptr, P, NROWS, 400, 100, 400, 400, 400);
            bvcomb_k<<<dim3(16, 7, 4), blk, 0, stream>>>(u, P, Ws_b, bvP);
            final1_part_k<4><<<dim3(32), blk, 0, stream>>>(bvP, F1_w, partM);
            final2_k<<<dim3(8), blk, 0, stream>>>(partM, F1_b, F2_w, F2_b, y);
            return;
        }
        // cooperative unsupported: full discrete big path (round-8)
        gemm2_k<0, 0, 1><<<dim3(4, 64, 4), blk, 0, stream>>>(
            nullptr, x1, x2, emb, Wh_w, nullptr, nullptr, nullptr,
            nullptr, nullptr, P, NROWS, 200, 50, 200, 200, 200);
        hcomb_k<<<dim3(1600), blk, 0, stream>>>(P, Wh_b, h);
        gemm2_k<1, 0, 0><<<dim3(10, 64, 4), blk, 0, stream>>>(
            h, nullptr, nullptr, nullptr, W1_w, W2_w, Wf2_w, nullptr,
            nullptr, nullptr, P, NROWS, 600, 50, 200, 200, 600);
        p3comb_k<<<dim3(4800), blk, 0, stream>>>(P, bvec, Wf2_b, cptr, hP);
        attn_part4_k<<<dim3(2048), blk, 0, stream>>>(h, hP, cptr, x1, x2, P, hsumP);
        attn_comb4_k<<<dim3(512), blk, 0, stream>>>(P, hsumP, x1, x2, sfw, sbw);
        gemm2_k<0, 0, 0><<<dim3(4, 128, 4), blk, 0, stream>>>(
            sfw, nullptr, nullptr, nullptr, Wf1_w, nullptr, nullptr, nullptr,
            nullptr, nullptr, P, 2 * NROWS, 200, 50, 200, 200, 200);
        ugate_k<<<dim3(3200), blk, 0, stream>>>(P, h, hP, sfw, u);
        gemm2_k<0, 0, 0><<<dim3(7, 64, 4), blk, 0, stream>>>(
            u, nullptr, nullptr, nullptr, Ws1_w, nullptr, nullptr, nullptr,
            nullptr, nullptr, P, NROWS, 400, 100, 400, 400, 400);
        v1comb_k<<<dim3(3200), blk, 0, stream>>>(P, Ws1_b, v1);
        gemm2_k<0, 0, 0><<<dim3(7, 64, 4), blk, 0, stream>>>(
            v1, nullptr, nullptr, nullptr, Ws_w, nullptr, nullptr, nullptr,
            nullptr, nullptr, P, NROWS, 400, 100, 400, 400, 400);
        bvcomb_k<<<dim3(16, 7, 4), blk, 0, stream>>>(u, P, Ws_b, bvP);
        final1_part_k<4><<<dim3(32), blk, 0, stream>>>(bvP, F1_w, partM);
        final2_k<<<dim3(8), blk, 0, stream>>>(partM, F1_b, F2_w, F2_b, y);
        return;
    }

    // tiny-ws fallback: simple unsplit path
    gemm2_k<0, 1, 1><<<dim3(4, 64), blk, 0, stream>>>(
        nullptr, x1, x2, emb, Wh_w, nullptr, nullptr, Wh_b,
        nullptr, nullptr, h, NROWS, 200, 200, 200, 200, 200);
    gemm2_k<1, 3, 0><<<dim3(10, 64), blk, 0, stream>>>(
        h, nullptr, nullptr, nullptr, W1_w, W2_w, Wf2_w, Wf2_b,
        bvec, cptr, hP, NROWS, 600, 200, 200, 200, 600);
    attn_part4_k<<<dim3(2048), blk, 0, stream>>>(h, hP, cptr, x1, x2, P, hsumP);
    attn_comb4_k<<<dim3(512), blk, 0, stream>>>(P, hsumP, x1, x2, sfw, sbw);
    gemm2_k<0, 2, 0><<<dim3(4, 128), blk, 0, stream>>>(
        sfw, nullptr, nullptr, nullptr, Wf1_w, nullptr, nullptr, nullptr,
        h, hP, u, 2 * NROWS, 200, 200, 200, 200, 400);
    gemm2_k<0, 1, 0><<<dim3(7, 64), blk, 0, stream>>>(
        u, nullptr, nullptr, nullptr, Ws1_w, nullptr, nullptr, Ws1_b,
        nullptr, nullptr, v1, NROWS, 400, 400, 400, 400, 400);
    gemm2_k<0, 0, 0><<<dim3(7, 64), blk, 0, stream>>>(
        v1, nullptr, nullptr, nullptr, Ws_w, nullptr, nullptr, Ws_b,
        nullptr, nullptr, P, NROWS, 400, 400, 400, 400, 400);
    bvcomb_k<<<dim3(16, 7, 4), blk, 0, stream>>>(u, P, Ws_b, bvP);
    final1_part_k<4><<<dim3(32), blk, 0, stream>>>(bvP, F1_w, partM);
    final2_k<<<dim3(8), blk, 0, stream>>>(partM, F1_b, F2_w, F2_b, y);
}

// Round 10
// 180.347 us; speedup vs baseline: 24.6523x; 24.6523x over previous
//
#include <hip/hip_runtime.h>
#include <hip/hip_bf16.h>
#include <math.h>

// Problem constants
#define B 8
#define L 128
#define D 200
#define NROWS 2048          // 2 sequences * B * L
#define PAD_ID 1
#define LOG2E 1.4426950408889634f

// ==================== K1: fused emb->h->proj3 (row-local) ====================
// 256 blocks x 8 rows. h = elu(emb[x]@Wh + b); hP = [(h@W1+bvec)*k1 | (h@W2)*k1 | h@Wf2+Wf2_b]
__global__ __launch_bounds__(256)
void fused_hproj_k(const int* __restrict__ x1, const int* __restrict__ x2,
                   const float* __restrict__ emb,
                   const float* __restrict__ Wh_w, const float* __restrict__ Wh_b,
                   const float* __restrict__ W1_w, const float* __restrict__ W2_w,
                   const float* __restrict__ Wf2_w, const float* __restrict__ bvec,
                   const float* __restrict__ Wf2_b, const float* __restrict__ cptr,
                   float* __restrict__ h, float* __restrict__ hP)
{
    __shared__ float As[8][200];
    __shared__ float Hs[8][200];
    const int r0 = blockIdx.x * 8;
    const int tid = threadIdx.x;

    for (int idx = tid; idx < 1600; idx += 256) {
        const int r = idx / 200, k = idx - r * 200;
        const int row = r0 + r;
        const int id = (row < 1024) ? x1[row] : x2[row - 1024];
        As[r][k] = emb[id * 200 + k];
    }
    __syncthreads();

    const int c = tid;
    if (c < 200) {
        float acc[8] = {};
        for (int k4 = 0; k4 < 50; ++k4) {
            float a[8][4];
            #pragma unroll
            for (int r = 0; r < 8; ++r) {
                const float4 v = *(const float4*)&As[r][k4 * 4];
                a[r][0] = v.x; a[r][1] = v.y; a[r][2] = v.z; a[r][3] = v.w;
            }
            #pragma unroll
            for (int kk = 0; kk < 4; ++kk) {
                const float w = Wh_w[(k4 * 4 + kk) * 200 + c];
                #pragma unroll
                for (int r = 0; r < 8; ++r) acc[r] = fmaf(a[r][kk], w, acc[r]);
            }
        }
        const float bb = Wh_b[c];
        #pragma unroll
        for (int r = 0; r < 8; ++r) {
            float v = acc[r] + bb;
            v = (v > 0.f) ? v : expm1f(v);
            Hs[r][c] = v;
            h[(r0 + r) * 200 + c] = v;
        }
    }
    __syncthreads();
    if (c < 200) {
        float a1[8] = {}, a2[8] = {}, a3[8] = {};
        for (int k4 = 0; k4 < 50; ++k4) {
            float a[8][4];
            #pragma unroll
            for (int r = 0; r < 8; ++r) {
                const float4 v = *(const float4*)&Hs[r][k4 * 4];
                a[r][0] = v.x; a[r][1] = v.y; a[r][2] = v.z; a[r][3] = v.w;
            }
            #pragma unroll
            for (int kk = 0; kk < 4; ++kk) {
                const int k = k4 * 4 + kk;
                const float w1 = W1_w[k * 200 + c];
                const float w2 = W2_w[k * 200 + c];
                const float w3 = Wf2_w[k * 200 + c];
                #pragma unroll
                for (int r = 0; r < 8; ++r) {
                    a1[r] = fmaf(a[r][kk], w1, a1[r]);
                    a2[r] = fmaf(a[r][kk], w2, a2[r]);
                    a3[r] = fmaf(a[r][kk], w3, a3[r]);
                }
            }
        }
        const float k1 = 2.0f * LOG2E / cptr[0];
        const float bv_ = bvec[c], wb = Wf2_b[c];
        #pragma unroll
        for (int r = 0; r < 8; ++r) {
            hP[(r0 + r) * 600 + c]       = (a1[r] + bv_) * k1;
            hP[(r0 + r) * 600 + 200 + c] = a2[r] * k1;
            hP[(r0 + r) * 600 + 400 + c] = a3[r] + wb;
        }
    }
}

// ==================== K2: attention partials (4 queries x 32 keys) ====================
__global__ __launch_bounds__(256)
void attn_part4_k(const float* __restrict__ h, const float* __restrict__ hP,
                  const float* __restrict__ cptr,
                  const int* __restrict__ x1, const int* __restrict__ x2,
                  float* __restrict__ part, float* __restrict__ hsumP)
{
    const int blk = blockIdx.x;          // 0..2047
    const int jq  = blk & 3;
    const int qc  = (blk >> 2) & 31;
    const int sb  = blk >> 7;            // 0..15
    const int i0  = qc * 4;
    const int base = sb * 128;
    const int j0 = jq * 32, j1 = j0 + 32;
    const int d = threadIdx.x;
    const int* ids = (sb < 8) ? x1 : x2;
    const int loc0 = (sb & 7) * 128;

    const float cval = cptr[0];
    const float mcoef = -2.0f * cval * LOG2E;

    const unsigned long long km =
        __ballot(ids[loc0 + j0 + (threadIdx.x & 31)] == PAD_ID);

    float pq[4];
    #pragma unroll
    for (int q = 0; q < 4; ++q)
        pq[q] = (d < D) ? hP[(base + i0 + q) * 600 + d] : 0.f;

    float lf[4] = {}, af[4] = {}, lb[4] = {}, ab[4] = {};
    float hsum = 0.f;

    auto sc = [&](float p, float h2k) -> float {
        float e2 = __builtin_amdgcn_exp2f(p + h2k);
        return __builtin_amdgcn_exp2f(mcoef * __builtin_amdgcn_rcpf(e2 + 1.0f));
    };
    auto ldrow = [&](int j, float& h2k, float& hj) {
        h2k = 0.f; hj = 0.f;
        if (d < D) {
            h2k = hP[(base + j) * 600 + 200 + d];
            hj  = h[(base + j) * 200 + d];
        }
    };

    const int aEnd = (i0 < j1) ? i0 : j1;
    for (int j = j0; j < aEnd; j += 2) {
        float h2a, ha, h2b, hb;
        ldrow(j, h2a, ha); ldrow(j + 1, h2b, hb);
        hsum += ha + hb;
        if (!((km >> (j - j0)) & 1ull)) {
            #pragma unroll
            for (int q = 0; q < 4; ++q) {
                float w = sc(pq[q], h2a);
                lb[q] += w; ab[q] = fmaf(w, ha, ab[q]);
            }
        }
        if (!((km >> (j + 1 - j0)) & 1ull)) {
            #pragma unroll
            for (int q = 0; q < 4; ++q) {
                float w = sc(pq[q], h2b);
                lb[q] += w; ab[q] = fmaf(w, hb, ab[q]);
            }
        }
    }
    if (i0 >= j0 && i0 < j1) {
        #pragma unroll
        for (int jj = 0; jj < 4; ++jj) {
            const int j = i0 + jj;
            float h2a, ha;
            ldrow(j, h2a, ha);
            hsum += ha;
            if (!((km >> (j - j0)) & 1ull)) {
                #pragma unroll
                for (int q = 0; q < 4; ++q) {
                    if (jj == q) continue;
                    float w = sc(pq[q], h2a);
                    if (jj > q) { lf[q] += w; af[q] = fmaf(w, ha, af[q]); }
                    else        { lb[q] += w; ab[q] = fmaf(w, ha, ab[q]); }
                }
            }
        }
    }
    const int cs = (i0 + 4 > j0) ? i0 + 4 : j0;
    for (int j = cs; j < j1; j += 2) {
        float h2a, ha, h2b, hb;
        ldrow(j, h2a, ha); ldrow(j + 1, h2b, hb);
        hsum += ha + hb;
        if (!((km >> (j - j0)) & 1ull)) {
            #pragma unroll
            for (int q = 0; q < 4; ++q) {
                float w = sc(pq[q], h2a);
                lf[q] += w; af[q] = fmaf(w, ha, af[q]);
            }
        }
        if (!((km >> (j + 1 - j0)) & 1ull)) {
            #pragma unroll
            for (int q = 0; q < 4; ++q) {
                float w = sc(pq[q], h2b);
                lf[q] += w; af[q] = fmaf(w, hb, af[q]);
            }
        }
    }

    if (d < D) {
        float* pp = part + (size_t)blk * 3200;   // [blk][16][200]
        #pragma unroll
        for (int q = 0; q < 4; ++q) {
            pp[(q * 4 + 0) * 200 + d] = lf[q];
            pp[(q * 4 + 1) * 200 + d] = af[q];
            pp[(q * 4 + 2) * 200 + d] = lb[q];
            pp[(q * 4 + 3) * 200 + d] = ab[q];
        }
        hsumP[(jq * 16 + sb) * 200 + d] = hsum;
    }
}

// ==================== K3: fused post-attention chain (row-local) ====================
// 256 blocks; block handles 8 query rows (sb = bid/16, i0 = (bid%16)*8).
// parts -> s(LDS) -> Wf1 -> gate -> u(LDS) -> Ws1+elu -> v1(LDS) -> Ws -> bv partial.
__global__ __launch_bounds__(256)
void fused_post_k(const float* __restrict__ P, const float* __restrict__ hsumP,
                  const int* __restrict__ x1, const int* __restrict__ x2,
                  const float* __restrict__ h, const float* __restrict__ hP,
                  const float* __restrict__ Wf1_w,
                  const float* __restrict__ Ws1_w, const float* __restrict__ Ws1_b,
                  const float* __restrict__ Ws_w, const float* __restrict__ Ws_b,
                  float* __restrict__ bvP)
{
    __shared__ float sS[16][200];   // 8 fw rows | 8 bw rows
    __shared__ float uS[8][400];
    __shared__ float v1S[8][400];
    const int bid = blockIdx.x;       // 0..255
    const int sb = bid >> 4;          // 0..15
    const int qp = bid & 15;          // 0..15
    const int i0 = qp * 8;
    const int base = sb * 128;
    const int tid = threadIdx.x;
    const int* ids = (sb < 8) ? x1 : x2;
    const int loc0 = (sb & 7) * 128;
    const int c = tid;

    // Phase 1: combine attention partials -> s rows
    if (c < 200) {
        float hs = 0.f;
        #pragma unroll
        for (int jq = 0; jq < 4; ++jq) hs += hsumP[(jq * 16 + sb) * 200 + c];
        const float fb = hs * (1.0f / 128.0f);
        #pragma unroll
        for (int q = 0; q < 8; ++q) {
            const int row = i0 + q;               // 0..127 within sb
            const int qc = row >> 2, qq = row & 3;
            const bool mi = (ids[loc0 + row] == PAD_ID);
            float lf = 0.f, af = 0.f, lb = 0.f, ab = 0.f;
            #pragma unroll
            for (int jq = 0; jq < 4; ++jq) {
                const float* pp = P + (size_t)(sb * 128 + qc * 4 + jq) * 3200
                                    + (qq * 4) * 200;
                lf += pp[c]; af += pp[200 + c]; lb += pp[400 + c]; ab += pp[600 + c];
            }
            sS[q][c]     = (!mi && lf > 0.f) ? af / lf : fb;
            sS[8 + q][c] = (!mi && lb > 0.f) ? ab / lb : fb;
        }
    }
    __syncthreads();

    // Phase 2: g = s @ Wf1 (16 rows x 200 cols, K=200); gate -> uS
    if (c < 200) {
        float acc[16] = {};
        for (int k4 = 0; k4 < 50; ++k4) {
            float a[16][4];
            #pragma unroll
            for (int r = 0; r < 16; ++r) {
                const float4 v = *(const float4*)&sS[r][k4 * 4];
                a[r][0] = v.x; a[r][1] = v.y; a[r][2] = v.z; a[r][3] = v.w;
            }
            #pragma unroll
            for (int kk = 0; kk < 4; ++kk) {
                const float w = Wf1_w[(k4 * 4 + kk) * 200 + c];
                #pragma unroll
                for (int r = 0; r < 16; ++r) acc[r] = fmaf(a[r][kk], w, acc[r]);
            }
        }
        #pragma unroll
        for (int q = 0; q < 8; ++q) {
            const int sr = base + i0 + q;
            const float hf2 = hP[sr * 600 + 400 + c];
            const float hv  = h[sr * 200 + c];
            const float ffw = 1.0f / (1.0f + __expf(-(acc[q] + hf2)));
            const float fbw = 1.0f / (1.0f + __expf(-(acc[8 + q] + hf2)));
            uS[q][c]       = ffw * hv + (1.f - ffw) * sS[q][c];
            uS[q][200 + c] = fbw * hv + (1.f - fbw) * sS[8 + q][c];
        }
    }
    __syncthreads();

    // Phase 3: v1 = elu(u @ Ws1 + b)  (8 rows x 400 cols, K=400)
    if (c < 200) {
        float a0[8] = {}, a1[8] = {};
        for (int k4 = 0; k4 < 100; ++k4) {
            float a[8][4];
            #pragma unroll
            for (int r = 0; r < 8; ++r) {
                const float4 v = *(const float4*)&uS[r][k4 * 4];
                a[r][0] = v.x; a[r][1] = v.y; a[r][2] = v.z; a[r][3] = v.w;
            }
            #pragma unroll
            for (int kk = 0; kk < 4; ++kk) {
                const int k = k4 * 4 + kk;
                const float w0 = Ws1_w[k * 400 + c];
                const float w1 = Ws1_w[k * 400 + c + 200];
                #pragma unroll
                for (int r = 0; r < 8; ++r) {
                    a0[r] = fmaf(a[r][kk], w0, a0[r]);
                    a1[r] = fmaf(a[r][kk], w1, a1[r]);
                }
            }
        }
        const float b0 = Ws1_b[c], b1 = Ws1_b[c + 200];
        #pragma unroll
        for (int r = 0; r < 8; ++r) {
            float v0 = a0[r] + b0; v0 = (v0 > 0.f) ? v0 : expm1f(v0);
            float v1v = a1[r] + b1; v1v = (v1v > 0.f) ? v1v : expm1f(v1v);
            v1S[r][c] = v0; v1S[r][c + 200] = v1v;
        }
    }
    __syncthreads();

    // Phase 4: atts = v1 @ Ws + b; bv partial = sum_r u*atts
    if (c < 200) {
        float a0[8] = {}, a1[8] = {};
        for (int k4 = 0; k4 < 100; ++k4) {
            float a[8][4];
            #pragma unroll
            for (int r = 0; r < 8; ++r) {
                const float4 v = *(const float4*)&v1S[r][k4 * 4];
                a[r][0] = v.x; a[r][1] = v.y; a[r][2] = v.z; a[r][3] = v.w;
            }
            #pragma unroll
            for (int kk = 0; kk < 4; ++kk) {
                const int k = k4 * 4 + kk;
                const float w0 = Ws_w[k * 400 + c];
                const float w1 = Ws_w[k * 400 + c + 200];
                #pragma unroll
                for (int r = 0; r < 8; ++r) {
                    a0[r] = fmaf(a[r][kk], w0, a0[r]);
                    a1[r] = fmaf(a[r][kk], w1, a1[r]);
                }
            }
        }
        const float b0 = Ws_b[c], b1 = Ws_b[c + 200];
        float s0 = 0.f, s1 = 0.f;
        #pragma unroll
        for (int r = 0; r < 8; ++r) {
            s0 = fmaf(uS[r][c],       a0[r] + b0, s0);
            s1 = fmaf(uS[r][c + 200], a1[r] + b1, s1);
        }
        bvP[bid * 400 + c]       = s0;
        bvP[bid * 400 + c + 200] = s1;
    }
}

// ==================== K4/K5: final MLP ====================
// bvP: [256][400], block (sb*16 + qp). bv[sb] = sum over 16 qp parts.
__global__ __launch_bounds__(256)
void final1_part_k(const float* __restrict__ bvP, const float* __restrict__ F1w,
                   float* __restrict__ part)
{
    __shared__ float feats[8][50];
    const int bid = blockIdx.x;       // 0..31
    const int seg = bid >> 3;
    const int kr0 = (bid & 7) * 50;
    const int tid = threadIdx.x;
    for (int idx = tid; idx < 400; idx += 256) {
        const int b = idx / 50, kk = idx - b * 50;
        float cv = 0.f, rv = 0.f;
        #pragma unroll
        for (int p = 0; p < 16; ++p) {
            cv += bvP[(b * 16 + p) * 400 + kr0 + kk];
            rv += bvP[((8 + b) * 16 + p) * 400 + kr0 + kk];
        }
        feats[b][kk] = (seg == 0) ? cv : (seg == 1) ? rv
                     : (seg == 2) ? (cv - rv) : (cv * rv);
    }
    __syncthreads();
    const int n = tid;
    if (n >= 200) return;
    const int kbase = seg * 400 + kr0;
    float acc[8] = {};
    #pragma unroll 5
    for (int kk = 0; kk < 50; ++kk) {
        const float w = F1w[(kbase + kk) * 200 + n];
        #pragma unroll
        for (int b = 0; b < 8; ++b)
            acc[b] = fmaf(feats[b][kk], w, acc[b]);
    }
    #pragma unroll
    for (int b = 0; b < 8; ++b)
        part[(bid * 8 + b) * 200 + n] = acc[b];
}

__global__ __launch_bounds__(256)
void final2_k(const float* __restrict__ part, const float* __restrict__ F1b,
              const float* __restrict__ F2w, const float* __restrict__ F2b,
              float* __restrict__ y)
{
    __shared__ float red[256];
    const int b = blockIdx.x, tid = threadIdx.x;
    float v = 0.f;
    if (tid < 200) {
        float s = F1b[tid];
        #pragma unroll 8
        for (int t = 0; t < 32; ++t)
            s += part[(t * 8 + b) * 200 + tid];
        v = fmaxf(s, 0.f) * F2w[tid];
    }
    red[tid] = v;
    __syncthreads();
    for (int off = 128; off; off >>= 1) {
        if (tid < off) red[tid] += red[tid + off];
        __syncthreads();
    }
    if (tid == 0) y[b] = red[0] + F2b[0];
}

extern "C" void kernel_launch(void* const* d_in, const int* in_sizes, int n_in,
                              void* d_out, int out_size, void* d_ws, size_t ws_size,
                              hipStream_t stream)
{
    const int*   x1    = (const int*)d_in[0];
    const int*   x2    = (const int*)d_in[1];
    const float* emb   = (const float*)d_in[2];
    const float* Wh_w  = (const float*)d_in[3];
    const float* Wh_b  = (const float*)d_in[4];
    const float* W1_w  = (const float*)d_in[5];
    const float* W2_w  = (const float*)d_in[6];
    const float* bvec  = (const float*)d_in[7];
    const float* cptr  = (const float*)d_in[8];
    const float* Wf1_w = (const float*)d_in[9];
    const float* Wf2_w = (const float*)d_in[10];
    const float* Wf2_b = (const float*)d_in[11];
    const float* Ws1_w = (const float*)d_in[12];
    const float* Ws1_b = (const float*)d_in[13];
    const float* Ws_w  = (const float*)d_in[14];
    const float* Ws_b  = (const float*)d_in[15];
    const float* F1_w  = (const float*)d_in[16];
    const float* F1_b  = (const float*)d_in[17];
    const float* F2_w  = (const float*)d_in[18];
    const float* F2_b  = (const float*)d_in[19];
    float* y = (float*)d_out;

    float* ws = (float*)d_ws;
    float* h     = ws;                    // 409600
    float* hP    = h     + 409600;        // 1228800
    float* hsumP = hP    + 1228800;       // 12800
    float* bvP   = hsumP + 12800;         // 102400
    float* partM = bvP   + 102400;        // 51200
    float* P     = partM + 51200;         // 6553600 (attention partials)
    // total 8,358,400 floats = 33.4 MB (ws is ~268 MB per harness fills)

    dim3 blk(256);

    fused_hproj_k<<<dim3(256), blk, 0, stream>>>(
        x1, x2, emb, Wh_w, Wh_b, W1_w, W2_w, Wf2_w, bvec, Wf2_b, cptr, h, hP);
    attn_part4_k<<<dim3(2048), blk, 0, stream>>>(h, hP, cptr, x1, x2, P, hsumP);
    fused_post_k<<<dim3(256), blk, 0, stream>>>(
        P, hsumP, x1, x2, h, hP, Wf1_w, Ws1_w, Ws1_b, Ws_w, Ws_b, bvP);
    final1_part_k<<<dim3(32), blk, 0, stream>>>(bvP, F1_w, partM);
    final2_k<<<dim3(8), blk, 0, stream>>>(partM, F1_b, F2_w, F2_b, y);
}

// Round 11
// 140.263 us; speedup vs baseline: 31.6973x; 1.2858x over previous
//
#include <hip/hip_runtime.h>
#include <hip/hip_bf16.h>
#include <math.h>

// Problem constants
#define B 8
#define L 128
#define D 200
#define NROWS 2048          // 2 sequences * B * L
#define PAD_ID 1
#define LOG2E 1.4426950408889634f

// ==================== K1: fused emb->h->proj3 (row-local, 4 rows/block) =============
// grid 512. h = elu(emb[x]@Wh + b); hP = [(h@W1+bvec)*k1 | (h@W2)*k1 | h@Wf2+Wf2_b]
__global__ __launch_bounds__(256)
void fused_hproj_k(const int* __restrict__ x1, const int* __restrict__ x2,
                   const float* __restrict__ emb,
                   const float* __restrict__ Wh_w, const float* __restrict__ Wh_b,
                   const float* __restrict__ W1_w, const float* __restrict__ W2_w,
                   const float* __restrict__ Wf2_w, const float* __restrict__ bvec,
                   const float* __restrict__ Wf2_b, const float* __restrict__ cptr,
                   float* __restrict__ h, float* __restrict__ hP)
{
    __shared__ float As[4][200];
    __shared__ float Hs[4][200];
    const int r0 = blockIdx.x * 4;
    const int tid = threadIdx.x;

    for (int idx = tid; idx < 800; idx += 256) {
        const int r = idx / 200, k = idx - r * 200;
        const int row = r0 + r;
        const int id = (row < 1024) ? x1[row] : x2[row - 1024];
        As[r][k] = emb[id * 200 + k];
    }
    __syncthreads();

    const int c = tid;
    if (c < 200) {
        float acc[4] = {};
        for (int k4 = 0; k4 < 50; ++k4) {
            float a[4][4];
            #pragma unroll
            for (int r = 0; r < 4; ++r) {
                const float4 v = *(const float4*)&As[r][k4 * 4];
                a[r][0] = v.x; a[r][1] = v.y; a[r][2] = v.z; a[r][3] = v.w;
            }
            #pragma unroll
            for (int kk = 0; kk < 4; ++kk) {
                const float w = Wh_w[(k4 * 4 + kk) * 200 + c];
                #pragma unroll
                for (int r = 0; r < 4; ++r) acc[r] = fmaf(a[r][kk], w, acc[r]);
            }
        }
        const float bb = Wh_b[c];
        #pragma unroll
        for (int r = 0; r < 4; ++r) {
            float v = acc[r] + bb;
            v = (v > 0.f) ? v : expm1f(v);
            Hs[r][c] = v;
            h[(r0 + r) * 200 + c] = v;
        }
    }
    __syncthreads();
    if (c < 200) {
        float a1[4] = {}, a2[4] = {}, a3[4] = {};
        for (int k4 = 0; k4 < 50; ++k4) {
            float a[4][4];
            #pragma unroll
            for (int r = 0; r < 4; ++r) {
                const float4 v = *(const float4*)&Hs[r][k4 * 4];
                a[r][0] = v.x; a[r][1] = v.y; a[r][2] = v.z; a[r][3] = v.w;
            }
            #pragma unroll
            for (int kk = 0; kk < 4; ++kk) {
                const int k = k4 * 4 + kk;
                const float w1 = W1_w[k * 200 + c];
                const float w2 = W2_w[k * 200 + c];
                const float w3 = Wf2_w[k * 200 + c];
                #pragma unroll
                for (int r = 0; r < 4; ++r) {
                    a1[r] = fmaf(a[r][kk], w1, a1[r]);
                    a2[r] = fmaf(a[r][kk], w2, a2[r]);
                    a3[r] = fmaf(a[r][kk], w3, a3[r]);
                }
            }
        }
        const float k1 = 2.0f * LOG2E / cptr[0];
        const float bv_ = bvec[c], wb = Wf2_b[c];
        #pragma unroll
        for (int r = 0; r < 4; ++r) {
            hP[(r0 + r) * 600 + c]       = (a1[r] + bv_) * k1;
            hP[(r0 + r) * 600 + 200 + c] = a2[r] * k1;
            hP[(r0 + r) * 600 + 400 + c] = a3[r] + wb;
        }
    }
}

// ==================== K2: attention partials (4 queries x 32 keys) ====================
__global__ __launch_bounds__(256)
void attn_part4_k(const float* __restrict__ h, const float* __restrict__ hP,
                  const float* __restrict__ cptr,
                  const int* __restrict__ x1, const int* __restrict__ x2,
                  float* __restrict__ part, float* __restrict__ hsumP)
{
    const int blk = blockIdx.x;          // 0..2047
    const int jq  = blk & 3;
    const int qc  = (blk >> 2) & 31;
    const int sb  = blk >> 7;            // 0..15
    const int i0  = qc * 4;
    const int base = sb * 128;
    const int j0 = jq * 32, j1 = j0 + 32;
    const int d = threadIdx.x;
    const int* ids = (sb < 8) ? x1 : x2;
    const int loc0 = (sb & 7) * 128;

    const float cval = cptr[0];
    const float mcoef = -2.0f * cval * LOG2E;

    const unsigned long long km =
        __ballot(ids[loc0 + j0 + (threadIdx.x & 31)] == PAD_ID);

    float pq[4];
    #pragma unroll
    for (int q = 0; q < 4; ++q)
        pq[q] = (d < D) ? hP[(base + i0 + q) * 600 + d] : 0.f;

    float lf[4] = {}, af[4] = {}, lb[4] = {}, ab[4] = {};
    float hsum = 0.f;

    auto sc = [&](float p, float h2k) -> float {
        float e2 = __builtin_amdgcn_exp2f(p + h2k);
        return __builtin_amdgcn_exp2f(mcoef * __builtin_amdgcn_rcpf(e2 + 1.0f));
    };
    auto ldrow = [&](int j, float& h2k, float& hj) {
        h2k = 0.f; hj = 0.f;
        if (d < D) {
            h2k = hP[(base + j) * 600 + 200 + d];
            hj  = h[(base + j) * 200 + d];
        }
    };

    const int aEnd = (i0 < j1) ? i0 : j1;
    for (int j = j0; j < aEnd; j += 2) {
        float h2a, ha, h2b, hb;
        ldrow(j, h2a, ha); ldrow(j + 1, h2b, hb);
        hsum += ha + hb;
        if (!((km >> (j - j0)) & 1ull)) {
            #pragma unroll
            for (int q = 0; q < 4; ++q) {
                float w = sc(pq[q], h2a);
                lb[q] += w; ab[q] = fmaf(w, ha, ab[q]);
            }
        }
        if (!((km >> (j + 1 - j0)) & 1ull)) {
            #pragma unroll
            for (int q = 0; q < 4; ++q) {
                float w = sc(pq[q], h2b);
                lb[q] += w; ab[q] = fmaf(w, hb, ab[q]);
            }
        }
    }
    if (i0 >= j0 && i0 < j1) {
        #pragma unroll
        for (int jj = 0; jj < 4; ++jj) {
            const int j = i0 + jj;
            float h2a, ha;
            ldrow(j, h2a, ha);
            hsum += ha;
            if (!((km >> (j - j0)) & 1ull)) {
                #pragma unroll
                for (int q = 0; q < 4; ++q) {
                    if (jj == q) continue;
                    float w = sc(pq[q], h2a);
                    if (jj > q) { lf[q] += w; af[q] = fmaf(w, ha, af[q]); }
                    else        { lb[q] += w; ab[q] = fmaf(w, ha, ab[q]); }
                }
            }
        }
    }
    const int cs = (i0 + 4 > j0) ? i0 + 4 : j0;
    for (int j = cs; j < j1; j += 2) {
        float h2a, ha, h2b, hb;
        ldrow(j, h2a, ha); ldrow(j + 1, h2b, hb);
        hsum += ha + hb;
        if (!((km >> (j - j0)) & 1ull)) {
            #pragma unroll
            for (int q = 0; q < 4; ++q) {
                float w = sc(pq[q], h2a);
                lf[q] += w; af[q] = fmaf(w, ha, af[q]);
            }
        }
        if (!((km >> (j + 1 - j0)) & 1ull)) {
            #pragma unroll
            for (int q = 0; q < 4; ++q) {
                float w = sc(pq[q], h2b);
                lf[q] += w; af[q] = fmaf(w, hb, af[q]);
            }
        }
    }

    if (d < D) {
        float* pp = part + (size_t)blk * 3200;   // [blk][16][200]
        #pragma unroll
        for (int q = 0; q < 4; ++q) {
            pp[(q * 4 + 0) * 200 + d] = lf[q];
            pp[(q * 4 + 1) * 200 + d] = af[q];
            pp[(q * 4 + 2) * 200 + d] = lb[q];
            pp[(q * 4 + 3) * 200 + d] = ab[q];
        }
        hsumP[(jq * 16 + sb) * 200 + d] = hsum;
    }
}

// ==================== K3: fused post-attention chain (4 rows/block, grid 512) ========
// block = sb(16) x qp(32); rows i0..i0+3. parts -> s(LDS) -> Wf1 -> gate -> u(LDS)
// -> Ws1+elu -> v1(LDS) -> Ws -> bv partial.
__global__ __launch_bounds__(256)
void fused_post_k(const float* __restrict__ P, const float* __restrict__ hsumP,
                  const int* __restrict__ x1, const int* __restrict__ x2,
                  const float* __restrict__ h, const float* __restrict__ hP,
                  const float* __restrict__ Wf1_w,
                  const float* __restrict__ Ws1_w, const float* __restrict__ Ws1_b,
                  const float* __restrict__ Ws_w, const float* __restrict__ Ws_b,
                  float* __restrict__ bvP)
{
    __shared__ float sS[8][200];    // 4 fw rows | 4 bw rows
    __shared__ float uS[4][400];
    __shared__ float v1S[4][400];
    const int bid = blockIdx.x;       // 0..511
    const int sb = bid >> 5;          // 0..15
    const int qp = bid & 31;          // 0..31 (== attention query-chunk qc)
    const int i0 = qp * 4;
    const int base = sb * 128;
    const int tid = threadIdx.x;
    const int* ids = (sb < 8) ? x1 : x2;
    const int loc0 = (sb & 7) * 128;
    const int c = tid;

    // Phase 1: combine attention partials -> s rows
    if (c < 200) {
        float hs = 0.f;
        #pragma unroll
        for (int jq = 0; jq < 4; ++jq) hs += hsumP[(jq * 16 + sb) * 200 + c];
        const float fb = hs * (1.0f / 128.0f);
        #pragma unroll
        for (int q = 0; q < 4; ++q) {
            const bool mi = (ids[loc0 + i0 + q] == PAD_ID);
            float lf = 0.f, af = 0.f, lb = 0.f, ab = 0.f;
            #pragma unroll
            for (int jq = 0; jq < 4; ++jq) {
                const float* pp = P + (size_t)(sb * 128 + qp * 4 + jq) * 3200
                                    + (q * 4) * 200;
                lf += pp[c]; af += pp[200 + c]; lb += pp[400 + c]; ab += pp[600 + c];
            }
            sS[q][c]     = (!mi && lf > 0.f) ? af / lf : fb;
            sS[4 + q][c] = (!mi && lb > 0.f) ? ab / lb : fb;
        }
    }
    __syncthreads();

    // Phase 2: g = s @ Wf1 (8 rows x 200 cols, K=200); gate -> uS
    if (c < 200) {
        float acc[8] = {};
        for (int k4 = 0; k4 < 50; ++k4) {
            float a[8][4];
            #pragma unroll
            for (int r = 0; r < 8; ++r) {
                const float4 v = *(const float4*)&sS[r][k4 * 4];
                a[r][0] = v.x; a[r][1] = v.y; a[r][2] = v.z; a[r][3] = v.w;
            }
            #pragma unroll
            for (int kk = 0; kk < 4; ++kk) {
                const float w = Wf1_w[(k4 * 4 + kk) * 200 + c];
                #pragma unroll
                for (int r = 0; r < 8; ++r) acc[r] = fmaf(a[r][kk], w, acc[r]);
            }
        }
        #pragma unroll
        for (int q = 0; q < 4; ++q) {
            const int sr = base + i0 + q;
            const float hf2 = hP[sr * 600 + 400 + c];
            const float hv  = h[sr * 200 + c];
            const float ffw = 1.0f / (1.0f + __expf(-(acc[q] + hf2)));
            const float fbw = 1.0f / (1.0f + __expf(-(acc[4 + q] + hf2)));
            uS[q][c]       = ffw * hv + (1.f - ffw) * sS[q][c];
            uS[q][200 + c] = fbw * hv + (1.f - fbw) * sS[4 + q][c];
        }
    }
    __syncthreads();

    // Phase 3: v1 = elu(u @ Ws1 + b)  (4 rows x 400 cols, K=400)
    if (c < 200) {
        float a0[4] = {}, a1[4] = {};
        for (int k4 = 0; k4 < 100; ++k4) {
            float a[4][4];
            #pragma unroll
            for (int r = 0; r < 4; ++r) {
                const float4 v = *(const float4*)&uS[r][k4 * 4];
                a[r][0] = v.x; a[r][1] = v.y; a[r][2] = v.z; a[r][3] = v.w;
            }
            #pragma unroll
            for (int kk = 0; kk < 4; ++kk) {
                const int k = k4 * 4 + kk;
                const float w0 = Ws1_w[k * 400 + c];
                const float w1 = Ws1_w[k * 400 + c + 200];
                #pragma unroll
                for (int r = 0; r < 4; ++r) {
                    a0[r] = fmaf(a[r][kk], w0, a0[r]);
                    a1[r] = fmaf(a[r][kk], w1, a1[r]);
                }
            }
        }
        const float b0 = Ws1_b[c], b1 = Ws1_b[c + 200];
        #pragma unroll
        for (int r = 0; r < 4; ++r) {
            float v0 = a0[r] + b0; v0 = (v0 > 0.f) ? v0 : expm1f(v0);
            float v1v = a1[r] + b1; v1v = (v1v > 0.f) ? v1v : expm1f(v1v);
            v1S[r][c] = v0; v1S[r][c + 200] = v1v;
        }
    }
    __syncthreads();

    // Phase 4: atts = v1 @ Ws + b; bv partial = sum_r u*atts
    if (c < 200) {
        float a0[4] = {}, a1[4] = {};
        for (int k4 = 0; k4 < 100; ++k4) {
            float a[4][4];
            #pragma unroll
            for (int r = 0; r < 4; ++r) {
                const float4 v = *(const float4*)&v1S[r][k4 * 4];
                a[r][0] = v.x; a[r][1] = v.y; a[r][2] = v.z; a[r][3] = v.w;
            }
            #pragma unroll
            for (int kk = 0; kk < 4; ++kk) {
                const int k = k4 * 4 + kk;
                const float w0 = Ws_w[k * 400 + c];
                const float w1 = Ws_w[k * 400 + c + 200];
                #pragma unroll
                for (int r = 0; r < 4; ++r) {
                    a0[r] = fmaf(a[r][kk], w0, a0[r]);
                    a1[r] = fmaf(a[r][kk], w1, a1[r]);
                }
            }
        }
        const float b0 = Ws_b[c], b1 = Ws_b[c + 200];
        float s0 = 0.f, s1 = 0.f;
        #pragma unroll
        for (int r = 0; r < 4; ++r) {
            s0 = fmaf(uS[r][c],       a0[r] + b0, s0);
            s1 = fmaf(uS[r][c + 200], a1[r] + b1, s1);
        }
        bvP[bid * 400 + c]       = s0;
        bvP[bid * 400 + c + 200] = s1;
    }
}

// ==================== K4/K5: final MLP ====================
// bvP: [512][400], block (sb*32 + qp). bv[sb] = sum over 32 qp parts.
__global__ __launch_bounds__(256)
void final1_part_k(const float* __restrict__ bvP, const float* __restrict__ F1w,
                   float* __restrict__ part)
{
    __shared__ float feats[8][50];
    const int bid = blockIdx.x;       // 0..31
    const int seg = bid >> 3;
    const int kr0 = (bid & 7) * 50;
    const int tid = threadIdx.x;
    for (int idx = tid; idx < 400; idx += 256) {
        const int b = idx / 50, kk = idx - b * 50;
        float cv = 0.f, rv = 0.f;
        #pragma unroll 8
        for (int p = 0; p < 32; ++p) {
            cv += bvP[(b * 32 + p) * 400 + kr0 + kk];
            rv += bvP[((8 + b) * 32 + p) * 400 + kr0 + kk];
        }
        feats[b][kk] = (seg == 0) ? cv : (seg == 1) ? rv
                     : (seg == 2) ? (cv - rv) : (cv * rv);
    }
    __syncthreads();
    const int n = tid;
    if (n >= 200) return;
    const int kbase = seg * 400 + kr0;
    float acc[8] = {};
    #pragma unroll 5
    for (int kk = 0; kk < 50; ++kk) {
        const float w = F1w[(kbase + kk) * 200 + n];
        #pragma unroll
        for (int b = 0; b < 8; ++b)
            acc[b] = fmaf(feats[b][kk], w, acc[b]);
    }
    #pragma unroll
    for (int b = 0; b < 8; ++b)
        part[(bid * 8 + b) * 200 + n] = acc[b];
}

__global__ __launch_bounds__(256)
void final2_k(const float* __restrict__ part, const float* __restrict__ F1b,
              const float* __restrict__ F2w, const float* __restrict__ F2b,
              float* __restrict__ y)
{
    __shared__ float red[256];
    const int b = blockIdx.x, tid = threadIdx.x;
    float v = 0.f;
    if (tid < 200) {
        float s = F1b[tid];
        #pragma unroll 8
        for (int t = 0; t < 32; ++t)
            s += part[(t * 8 + b) * 200 + tid];
        v = fmaxf(s, 0.f) * F2w[tid];
    }
    red[tid] = v;
    __syncthreads();
    for (int off = 128; off; off >>= 1) {
        if (tid < off) red[tid] += red[tid + off];
        __syncthreads();
    }
    if (tid == 0) y[b] = red[0] + F2b[0];
}

extern "C" void kernel_launch(void* const* d_in, const int* in_sizes, int n_in,
                              void* d_out, int out_size, void* d_ws, size_t ws_size,
                              hipStream_t stream)
{
    const int*   x1    = (const int*)d_in[0];
    const int*   x2    = (const int*)d_in[1];
    const float* emb   = (const float*)d_in[2];
    const float* Wh_w  = (const float*)d_in[3];
    const float* Wh_b  = (const float*)d_in[4];
    const float* W1_w  = (const float*)d_in[5];
    const float* W2_w  = (const float*)d_in[6];
    const float* bvec  = (const float*)d_in[7];
    const float* cptr  = (const float*)d_in[8];
    const float* Wf1_w = (const float*)d_in[9];
    const float* Wf2_w = (const float*)d_in[10];
    const float* Wf2_b = (const float*)d_in[11];
    const float* Ws1_w = (const float*)d_in[12];
    const float* Ws1_b = (const float*)d_in[13];
    const float* Ws_w  = (const float*)d_in[14];
    const float* Ws_b  = (const float*)d_in[15];
    const float* F1_w  = (const float*)d_in[16];
    const float* F1_b  = (const float*)d_in[17];
    const float* F2_w  = (const float*)d_in[18];
    const float* F2_b  = (const float*)d_in[19];
    float* y = (float*)d_out;

    float* ws = (float*)d_ws;
    float* h     = ws;                    // 409600
    float* hP    = h     + 409600;        // 1228800
    float* hsumP = hP    + 1228800;       // 12800
    float* bvP   = hsumP + 12800;         // 204800 (512*400)
    float* partM = bvP   + 204800;        // 51200
    float* P     = partM + 51200;         // 6553600 (attention partials)

    dim3 blk(256);

    fused_hproj_k<<<dim3(512), blk, 0, stream>>>(
        x1, x2, emb, Wh_w, Wh_b, W1_w, W2_w, Wf2_w, bvec, Wf2_b, cptr, h, hP);
    attn_part4_k<<<dim3(2048), blk, 0, stream>>>(h, hP, cptr, x1, x2, P, hsumP);
    fused_post_k<<<dim3(512), blk, 0, stream>>>(
        P, hsumP, x1, x2, h, hP, Wf1_w, Ws1_w, Ws1_b, Ws_w, Ws_b, bvP);
    final1_part_k<<<dim3(32), blk, 0, stream>>>(bvP, F1_w, partM);
    final2_k<<<dim3(8), blk, 0, stream>>>(partM, F1_b, F2_w, F2_b, y);
}